// Round 15
// baseline (604.878 us; speedup 1.0000x reference)
//
#include <hip/hip_runtime.h>

// ---------------------------------------------------------------------------
// Self-attention (B=4, S=4096, D=1024), fp32 in/out.
// R18 (resubmit — prior bench failed on GPU acquisition, never run):
//  R17's 32x32 qk REVERTED (absmax 4.54 — 4-VGPR i8 operand layout
//  unverified; do not re-roll blind). qk back to verified 16x16x64 path,
//  now at proj's measured-best occupancy shape: tile 128x64, 2-buf, 48KB
//  -> 3 blocks/CU (was 128x128/64KB/2 blocks). m114 cross-block overlap
//  hides the 2-phase barrier drain; R10 showed occupancy > depth for proj.
//  NOTE: MfmaUtil under-reports i8 (gfx94x formula) — qk true pipe ~58%.
// R16 kept: strength-reduced XOR addressing, split Q/K proj, pair-batched
// attention, PV 128x64, 2-buf/1-deep counted vmcnt.
// Numerics: proj 4-term dual-i8 (X=(xh+xl/256)/16, W=(wh+wl/256)/512),
// QK^T dual-i8 3-term, scores i16 (logit*32), V/PV bf16. absmax 0.08984375.
// ---------------------------------------------------------------------------

typedef __attribute__((ext_vector_type(4))) float floatx4;
typedef __attribute__((ext_vector_type(4))) int intx4;
typedef __attribute__((ext_vector_type(8))) short shortx8;
typedef unsigned short ushort_t;

__device__ __forceinline__ ushort_t f2bf(float f) {
  union { float f; unsigned u; } x; x.f = f;
  unsigned r = x.u + 0x7fffu + ((x.u >> 16) & 1u);  // RNE
  return (ushort_t)(r >> 16);
}
__device__ __forceinline__ float bf2f(ushort_t h) {
  union { unsigned u; float f; } x; x.u = ((unsigned)h) << 16; return x.f;
}
// fixed-point dual-int8 quant: v ~= (qh + ql/256) / 16   (activations, Q, K)
__device__ __forceinline__ void quant8(float v, char& qh, char& ql) {
  float vs = v * 16.0f;
  float h = rintf(vs);
  h = fminf(fmaxf(h, -127.f), 127.f);
  float l = rintf((vs - h) * 256.0f);
  l = fminf(fmaxf(l, -127.f), 127.f);
  qh = (char)(int)h; ql = (char)(int)l;
}
// weight quant: v ~= (qh + ql/256) / 512
__device__ __forceinline__ void quant8w(float v, char& qh, char& ql) {
  float vs = v * 512.0f;
  float h = rintf(vs);
  h = fminf(fmaxf(h, -127.f), 127.f);
  float l = rintf((vs - h) * 256.0f);
  l = fminf(fmaxf(l, -127.f), 127.f);
  qh = (char)(int)h; ql = (char)(int)l;
}

// Async global->LDS, 16B per lane (m97 lever). LDS dest = wave-uniform base
// + lane*16 (m104/m108); lane->LDS mapping contiguous in lane order.
__device__ __forceinline__ void gload_lds16(const void* g, void* l) {
  __builtin_amdgcn_global_load_lds(
      (__attribute__((address_space(1))) void*)(uintptr_t)g,
      (__attribute__((address_space(3))) void*)(unsigned)(uintptr_t)l,
      16, 0, 0);
}

// Counted vmcnt wait (T4). Never 0 in the main loop.
template<int N> __device__ __forceinline__ void wait_vm() {
  static_assert(N == 0 || N == 3 || N == 4 || N == 6 || N == 8, "bad vmcnt");
  if constexpr (N == 0)       asm volatile("s_waitcnt vmcnt(0)" ::: "memory");
  else if constexpr (N == 3)  asm volatile("s_waitcnt vmcnt(3)" ::: "memory");
  else if constexpr (N == 4)  asm volatile("s_waitcnt vmcnt(4)" ::: "memory");
  else if constexpr (N == 6)  asm volatile("s_waitcnt vmcnt(6)" ::: "memory");
  else if constexpr (N == 8)  asm volatile("s_waitcnt vmcnt(8)" ::: "memory");
}
__device__ __forceinline__ void barrier_fenced() {
  asm volatile("" ::: "memory");
  __builtin_amdgcn_s_barrier();
  asm volatile("" ::: "memory");
}

// ---------------- bf16 GEMM (V proj / PV): C = A * B^T ---------------------
// Tile BM=TM*32 x BN=TN*32, 256 threads = 4 waves 2x2. Double-buffered LDS,
// 1-deep prefetch, counted vmcnt, XOR buffer addressing.
// OMODE: 0 = C fp32 [z*sC+row*ldc+col]; 2 = C bf16 per-batch transposed.
// LMODE: 2 kend=roundup(sent(b0+z),128) (PV);
//        3 skip block if (row0&4095)>=roundup(sent(row0>>12),128) (V proj)
template<int TM, int TN, int OMODE, int LMODE>
__global__ __launch_bounds__(256)
void gemm_bt(const ushort_t* __restrict__ A0g, const ushort_t* __restrict__ B0g,
             void* __restrict__ C0v, int K, int lda, int ldc, long bstride,
             const int* __restrict__ lenp, int b0, long sA, long sB, long sC)
{
  constexpr int BM = TM * 32, BN = TN * 32;
  constexpr int LA = TM / 2, LB = TN / 2;
  constexpr int NL = LA + LB;
  constexpr unsigned ABUF = BM * 32 * 2;      // bytes per A buffer (pow2)
  constexpr unsigned BBUF = BN * 32 * 2;      // bytes per B buffer (pow2)
  __shared__ ushort_t As[2][BM][32];
  __shared__ ushort_t Bs[2][BN][32];

  const int tid = threadIdx.x;
  const int z = blockIdx.z;
  const long row0 = (long)blockIdx.x * BM;
  const long col0 = (long)blockIdx.y * BN;

  int kend = K;
  if constexpr (LMODE == 2) {
    const int sent = lenp[b0 + z] * 2;
    kend = (sent + 127) & ~127;
  } else if constexpr (LMODE == 3) {
    const int sent = lenp[row0 >> 12] * 2;
    if ((int)(row0 & 4095) >= ((sent + 127) & ~127)) return;
  }

  const int sr = tid >> 2, scol = (tid & 3) * 8;
  // per-stream global pointers, advanced += 32 elems (64B) per chunk
  const ushort_t* pA[LA];
  const ushort_t* pB[LB];
#pragma unroll
  for (int j = 0; j < LA; ++j)
    pA[j] = A0g + z * sA + (row0 + sr + j * 64) * (long)lda + scol;
#pragma unroll
  for (int j = 0; j < LB; ++j)
    pB[j] = B0g + z * sB + (col0 + sr + j * 64) * (long)K + scol;
  // LDS dest byte offsets (buf0), toggled by XOR
  unsigned dA = (unsigned)(sr * 32 + scol) * 2;
  unsigned dB = dA;

  const int wid = tid >> 6, lane = tid & 63;
  const int wm = (wid >> 1) * (BM / 2), wn = (wid & 1) * (BN / 2);
  const int lr = lane & 15, lq = lane >> 4;
  // LDS read byte offsets (buf0), toggled by XOR
  unsigned ra = (unsigned)((wm + lr) * 32 + lq * 8) * 2;
  unsigned rb = (unsigned)((wn + lr) * 32 + lq * 8) * 2;

  floatx4 acc[TM][TN] = {};

  auto stage = [&]() {
#pragma unroll
    for (int j = 0; j < LA; ++j)
      gload_lds16(pA[j], (char*)As + dA + j * 4096);
#pragma unroll
    for (int j = 0; j < LB; ++j)
      gload_lds16(pB[j], (char*)Bs + dB + j * 4096);
  };
  auto advance = [&]() {
#pragma unroll
    for (int j = 0; j < LA; ++j) pA[j] += 32;
#pragma unroll
    for (int j = 0; j < LB; ++j) pB[j] += 32;
  };

  const int nk = kend >> 5;
  stage(); advance();
  dA ^= ABUF; dB ^= BBUF;
  for (int t = 0; t < nk; ++t) {
    if (t + 1 < nk) { stage(); advance(); dA ^= ABUF; dB ^= BBUF; wait_vm<NL>(); }
    else            { wait_vm<0>(); }
    barrier_fenced();

    const char* Ab = (const char*)As + ra;
    const char* Bb = (const char*)Bs + rb;
    shortx8 af[TM], bf[TN];
#pragma unroll
    for (int tt = 0; tt < TM; ++tt)
      af[tt] = *(const shortx8*)(Ab + tt * 1024);
#pragma unroll
    for (int tt = 0; tt < TN; ++tt)
      bf[tt] = *(const shortx8*)(Bb + tt * 1024);
#pragma unroll
    for (int mt = 0; mt < TM; ++mt)
#pragma unroll
      for (int nt = 0; nt < TN; ++nt)
        acc[mt][nt] = __builtin_amdgcn_mfma_f32_16x16x32_bf16(af[mt], bf[nt], acc[mt][nt], 0, 0, 0);

    barrier_fenced();
    ra ^= ABUF; rb ^= BBUF;
  }

  // C/D layout (m89/m91): col = lane&15, row = (lane>>4)*4 + reg
#pragma unroll
  for (int mt = 0; mt < TM; ++mt) {
#pragma unroll
    for (int nt = 0; nt < TN; ++nt) {
      long col = col0 + wn + nt * 16 + lr;
      if constexpr (OMODE == 2) {
        long row = row0 + wm + mt * 16 + lq * 4;
        long bb = row >> 12, s = row & 4095;
        ushort4 pk;
        pk.x = f2bf(acc[mt][nt][0]); pk.y = f2bf(acc[mt][nt][1]);
        pk.z = f2bf(acc[mt][nt][2]); pk.w = f2bf(acc[mt][nt][3]);
        *(ushort4*)&((ushort_t*)C0v)[bb * bstride + col * ldc + s] = pk;
      } else {
#pragma unroll
        for (int r = 0; r < 4; ++r) {
          long row = row0 + wm + mt * 16 + lq * 4 + r;
          ((float*)C0v)[z * sC + row * ldc + col] = acc[mt][nt][r];
        }
      }
    }
  }
}

// ---------------- dual-i8 projection: C = X * W^T --------------------------
// X = (xh+xl/256)/16, W = (wh+wl/256)/512; 4 exact i32 accum terms:
//   v = (hh + cross/256 + ll/65536) / 8192 -> re-quant dual-i8 scale 16.
// Tile 128x64, K=1024 in 64-chunks. Dbuf 1-deep, XOR addressing.
// LMODE 0 = all rows (Q); LMODE 3 = row-block skip (K).
template<int LMODE>
__global__ __launch_bounds__(256)
void proj_i8(const char* __restrict__ Ah, const char* __restrict__ Al,
             const char* __restrict__ Bh, const char* __restrict__ Bl,
             char* __restrict__ Ch, char* __restrict__ Cl,
             const int* __restrict__ lenp)
{
  __shared__ char As[2][2][128][64];   // [buf][h/l]   buf stride 16384
  __shared__ char Bs[2][2][64][64];    // buf stride 8192
  const int tid = threadIdx.x;
  const long row0 = (long)blockIdx.x * 128;
  const long col0 = (long)blockIdx.y * 64;
  if constexpr (LMODE == 3) {
    const int sent = lenp[row0 >> 12] * 2;
    if ((int)(row0 & 4095) >= ((sent + 127) & ~127)) return;
  }

  const int sr = tid >> 2, sc16 = (tid & 3) * 16;
  const char* gA0a = Ah + (row0 + sr) * 1024 + sc16;
  const char* gA0b = gA0a + 65536;
  const char* gA1a = Al + (row0 + sr) * 1024 + sc16;
  const char* gA1b = gA1a + 65536;
  const char* gB0 = Bh + (col0 + sr) * 1024 + sc16;
  const char* gB1 = Bl + (col0 + sr) * 1024 + sc16;
  unsigned dA = (unsigned)(sr * 64 + sc16);   // + hl*8192 + j*4096
  unsigned dB = dA;                            // + hl*4096

  const int wid = tid >> 6, lane = tid & 63;
  const int wm = (wid >> 1) * 64, wn = (wid & 1) * 32;
  const int lr = lane & 15, lq = lane >> 4;
  unsigned ra = (unsigned)((wm + lr) * 64 + lq * 16);
  unsigned rb = (unsigned)((wn + lr) * 64 + lq * 16);

  intx4 acc1[4][2] = {};   // xh*wh
  intx4 acc2[4][2] = {};   // xh*wl + xl*wh   (/256)
  intx4 acc3[4][2] = {};   // xl*wl           (/65536)

  auto stage = [&]() {
    gload_lds16(gA0a, (char*)As + dA);
    gload_lds16(gA0b, (char*)As + dA + 4096);
    gload_lds16(gA1a, (char*)As + dA + 8192);
    gload_lds16(gA1b, (char*)As + dA + 8192 + 4096);
    gload_lds16(gB0, (char*)Bs + dB);
    gload_lds16(gB1, (char*)Bs + dB + 4096);
  };
  auto advance = [&]() {
    gA0a += 64; gA0b += 64; gA1a += 64; gA1b += 64; gB0 += 64; gB1 += 64;
  };

  stage(); advance();
  dA ^= 16384; dB ^= 8192;
  for (int t = 0; t < 16; ++t) {
    if (t + 1 < 16) { stage(); advance(); dA ^= 16384; dB ^= 8192; wait_vm<6>(); }
    else            { wait_vm<0>(); }
    barrier_fenced();

    const char* Ab = (const char*)As + ra;
    const char* Bb = (const char*)Bs + rb;
    intx4 ah[4], al[4], bh[2], bl[2];
#pragma unroll
    for (int tt = 0; tt < 4; ++tt) {
      ah[tt] = *(const intx4*)(Ab + tt * 1024);
      al[tt] = *(const intx4*)(Ab + 8192 + tt * 1024);
    }
#pragma unroll
    for (int tt = 0; tt < 2; ++tt) {
      bh[tt] = *(const intx4*)(Bb + tt * 1024);
      bl[tt] = *(const intx4*)(Bb + 4096 + tt * 1024);
    }
#pragma unroll
    for (int mt = 0; mt < 4; ++mt)
#pragma unroll
      for (int nt = 0; nt < 2; ++nt) {
        acc1[mt][nt] = __builtin_amdgcn_mfma_i32_16x16x64_i8(ah[mt], bh[nt], acc1[mt][nt], 0, 0, 0);
        acc2[mt][nt] = __builtin_amdgcn_mfma_i32_16x16x64_i8(ah[mt], bl[nt], acc2[mt][nt], 0, 0, 0);
        acc2[mt][nt] = __builtin_amdgcn_mfma_i32_16x16x64_i8(al[mt], bh[nt], acc2[mt][nt], 0, 0, 0);
        acc3[mt][nt] = __builtin_amdgcn_mfma_i32_16x16x64_i8(al[mt], bl[nt], acc3[mt][nt], 0, 0, 0);
      }
    barrier_fenced();
    ra ^= 16384; rb ^= 8192;
  }

#pragma unroll
  for (int mt = 0; mt < 4; ++mt)
#pragma unroll
    for (int nt = 0; nt < 2; ++nt) {
      long col = col0 + wn + nt * 16 + lr;
#pragma unroll
      for (int r = 0; r < 4; ++r) {
        long row = row0 + wm + mt * 16 + lq * 4 + r;
        float v = ((float)acc1[mt][nt][r]
                   + (float)acc2[mt][nt][r] * (1.0f / 256.0f)
                   + (float)acc3[mt][nt][r] * (1.0f / 65536.0f)) * (1.0f / 8192.0f);
        char qh, ql;
        quant8(v, qh, ql);
        Ch[row * 1024 + col] = qh;
        Cl[row * 1024 + col] = ql;
      }
    }
}

// ---------------- int8 QK^T -> i16 scores (logit*32) -----------------------
// Tile 128x64 (proj-shaped: 48KB, 3 blocks/CU), K=1024 in 64-chunks.
// 16x16x64 i8, 2 accums (hh, cross). Dbuf 1-deep, XOR addressing.
// blockIdx.z = batch within pair.
__global__ __launch_bounds__(256)
void qk_i8(const char* __restrict__ Qh, const char* __restrict__ Ql,
           const char* __restrict__ Kh, const char* __restrict__ Kl,
           short* __restrict__ sc, const int* __restrict__ lenp, int b0)
{
  __shared__ char As[2][2][128][64];   // buf stride 16384
  __shared__ char Bs[2][2][64][64];    // buf stride 8192
  const int tid = threadIdx.x;
  const int z = blockIdx.z;
  const long zo = (long)z * 4096 * 1024;
  const long row0 = (long)blockIdx.x * 128;
  const long col0 = (long)blockIdx.y * 64;
  const int sent = lenp[b0 + z] * 2;
  if (col0 >= sent) return;

  const int sr = tid >> 2, sc16 = (tid & 3) * 16;
  const char* gA0a = Qh + zo + (row0 + sr) * 1024 + sc16;
  const char* gA0b = gA0a + 65536;
  const char* gA1a = Ql + zo + (row0 + sr) * 1024 + sc16;
  const char* gA1b = gA1a + 65536;
  const char* gB0 = Kh + zo + (col0 + sr) * 1024 + sc16;
  const char* gB1 = Kl + zo + (col0 + sr) * 1024 + sc16;
  unsigned dA = (unsigned)(sr * 64 + sc16);
  unsigned dB = dA;

  const int wid = tid >> 6, lane = tid & 63;
  const int wm = (wid >> 1) * 64, wn = (wid & 1) * 32;
  const int lr = lane & 15, lq = lane >> 4;
  unsigned ra = (unsigned)((wm + lr) * 64 + lq * 16);
  unsigned rb = (unsigned)((wn + lr) * 64 + lq * 16);

  intx4 acc1[4][2] = {};   // qh*kh
  intx4 acc2[4][2] = {};   // qh*kl + ql*kh (shared scale /256)

  auto stage = [&]() {
    gload_lds16(gA0a, (char*)As + dA);
    gload_lds16(gA0b, (char*)As + dA + 4096);
    gload_lds16(gA1a, (char*)As + dA + 8192);
    gload_lds16(gA1b, (char*)As + dA + 8192 + 4096);
    gload_lds16(gB0, (char*)Bs + dB);
    gload_lds16(gB1, (char*)Bs + dB + 4096);
  };
  auto advance = [&]() {
    gA0a += 64; gA0b += 64; gA1a += 64; gA1b += 64; gB0 += 64; gB1 += 64;
  };

  stage(); advance();
  dA ^= 16384; dB ^= 8192;
  for (int t = 0; t < 16; ++t) {
    if (t + 1 < 16) { stage(); advance(); dA ^= 16384; dB ^= 8192; wait_vm<6>(); }
    else            { wait_vm<0>(); }
    barrier_fenced();

    const char* Ab = (const char*)As + ra;
    const char* Bb = (const char*)Bs + rb;
    intx4 ah[4], al[4], bh[2], bl[2];
#pragma unroll
    for (int tt = 0; tt < 4; ++tt) {
      ah[tt] = *(const intx4*)(Ab + tt * 1024);
      al[tt] = *(const intx4*)(Ab + 8192 + tt * 1024);
    }
#pragma unroll
    for (int tt = 0; tt < 2; ++tt) {
      bh[tt] = *(const intx4*)(Bb + tt * 1024);
      bl[tt] = *(const intx4*)(Bb + 4096 + tt * 1024);
    }
#pragma unroll
    for (int mt = 0; mt < 4; ++mt)
#pragma unroll
      for (int nt = 0; nt < 2; ++nt) {
        acc1[mt][nt] = __builtin_amdgcn_mfma_i32_16x16x64_i8(ah[mt], bh[nt], acc1[mt][nt], 0, 0, 0);
        acc2[mt][nt] = __builtin_amdgcn_mfma_i32_16x16x64_i8(ah[mt], bl[nt], acc2[mt][nt], 0, 0, 0);
        acc2[mt][nt] = __builtin_amdgcn_mfma_i32_16x16x64_i8(al[mt], bh[nt], acc2[mt][nt], 0, 0, 0);
      }
    barrier_fenced();
    ra ^= 16384; rb ^= 8192;
  }

  // i16 = logit*32 = acc1/8 + acc2/2048
  short* scz = sc + (long)z * 4096 * 4096;
#pragma unroll
  for (int mt = 0; mt < 4; ++mt)
#pragma unroll
    for (int nt = 0; nt < 2; ++nt) {
      long col = col0 + wn + nt * 16 + lr;
#pragma unroll
      for (int r = 0; r < 4; ++r) {
        long row = row0 + wm + mt * 16 + lq * 4 + r;
        float v = (float)acc1[mt][nt][r] * 0.125f
                + (float)acc2[mt][nt][r] * (1.0f / 2048.0f);
        v = fminf(fmaxf(v, -32000.0f), 32000.0f);
        scz[row * 4096 + col] = (short)(int)rintf(v);
      }
    }
}

// ---------------- casts ----------------------------------------------------
__global__ __launch_bounds__(256)
void cast_split(const float* __restrict__ in, ushort_t* __restrict__ hi,
                char* __restrict__ qh, char* __restrict__ ql, int n4) {
  int i = blockIdx.x * 256 + threadIdx.x;
  if (i < n4) {
    float4 v = ((const float4*)in)[i];
    ushort4 h;
    h.x = f2bf(v.x); h.y = f2bf(v.y); h.z = f2bf(v.z); h.w = f2bf(v.w);
    ((ushort4*)hi)[i] = h;
    char ax, bx, ay, by, az, bz, aw, bw;
    quant8(v.x, ax, bx); quant8(v.y, ay, by);
    quant8(v.z, az, bz); quant8(v.w, aw, bw);
    char4 a, b;
    a.x = ax; a.y = ay; a.z = az; a.w = aw;
    b.x = bx; b.y = by; b.z = bz; b.w = bw;
    ((char4*)qh)[i] = a;
    ((char4*)ql)[i] = b;
  }
}

__global__ __launch_bounds__(256)
void cast_wqk(const float* __restrict__ w0, const float* __restrict__ w1,
              char* __restrict__ h0, char* __restrict__ l0,
              char* __restrict__ h1, char* __restrict__ l1, int n4) {
  int i = blockIdx.x * 256 + threadIdx.x;
  if (i >= n4) return;
  const float* in = blockIdx.y ? w1 : w0;
  char* hp = blockIdx.y ? h1 : h0;
  char* lp = blockIdx.y ? l1 : l0;
  float4 v = ((const float4*)in)[i];
  char ax, bx, ay, by, az, bz, aw, bw;
  quant8w(v.x, ax, bx); quant8w(v.y, ay, by);
  quant8w(v.z, az, bz); quant8w(v.w, aw, bw);
  char4 a, b;
  a.x = ax; a.y = ay; a.z = az; a.w = aw;
  b.x = bx; b.y = by; b.z = bz; b.w = bw;
  ((char4*)hp)[i] = a;
  ((char4*)lp)[i] = b;
}

__global__ __launch_bounds__(256)
void cast_wv(const float* __restrict__ w, ushort_t* __restrict__ h, int n4) {
  int i = blockIdx.x * 256 + threadIdx.x;
  if (i >= n4) return;
  float4 v = ((const float4*)w)[i];
  ushort4 p;
  p.x = f2bf(v.x); p.y = f2bf(v.y); p.z = f2bf(v.z); p.w = f2bf(v.w);
  ((ushort4*)h)[i] = p;
}

// Masked softmax; reads i16 scores (logit*32), writes bf16 P in place.
// Handles a batch PAIR: rows 0..8191, b = b0 + (row>>12).
__global__ __launch_bounds__(256)
void softmax_rows(short* __restrict__ scores, const int* __restrict__ length, int b0) {
  const long row = blockIdx.x;
  const int b = b0 + (int)(row >> 12);
  short* p = scores + row * 4096;
  const int sent = length[b] * 2;
  const int sentceil = (sent + 127) & ~127;
  const int tid = threadIdx.x;
  float vals[16];
  float mx = -3.4e38f;
  int nj = 0;
  for (int c = tid; c < sentceil; c += 256) {
    float v = (float)p[c] * (1.0f / 32.0f);
    v = (c < sent) ? v : -2147483648.0f;   // NEG_BIG
    vals[nj++] = v;
    mx = fmaxf(mx, v);
  }
#pragma unroll
  for (int off = 32; off > 0; off >>= 1) mx = fmaxf(mx, __shfl_down(mx, off));
  __shared__ float red[8];
  if ((tid & 63) == 0) red[tid >> 6] = mx;
  __syncthreads();
  mx = fmaxf(fmaxf(red[0], red[1]), fmaxf(red[2], red[3]));
  float sum = 0.f;
  for (int j = 0; j < nj; ++j) { vals[j] = __expf(vals[j] - mx); sum += vals[j]; }
#pragma unroll
  for (int off = 32; off > 0; off >>= 1) sum += __shfl_down(sum, off);
  __syncthreads();
  if ((tid & 63) == 0) red[tid >> 6] = sum;
  __syncthreads();
  float inv = 1.0f / (red[0] + red[1] + red[2] + red[3]);
  ushort_t* pb = (ushort_t*)p;
  int j = 0;
  for (int c = tid; c < sentceil; c += 256) pb[c] = f2bf(vals[j++] * inv);
}

extern "C" void kernel_launch(void* const* d_in, const int* in_sizes, int n_in,
                              void* d_out, int out_size, void* d_ws, size_t ws_size,
                              hipStream_t stream) {
  const float* X   = (const float*)d_in[0];
  const int*   len = (const int*)d_in[1];
  const float* Wq  = (const float*)d_in[2];
  const float* Wk  = (const float*)d_in[3];
  const float* Wv  = (const float*)d_in[4];
  float* out = (float*)d_out;

  const int Bn = 4, S = 4096, D = 1024;
  const long MS = (long)Bn * S;

  char* w = (char*)d_ws;
  ushort_t* Xhi = (ushort_t*)w; w += MS * D * 2;   // dead after V proj
  char* Xh8 = w; w += MS * D;                      // dead after proj
  char* Xl8 = w; w += MS * D;                      // dead after proj
  char* Qh8 = w; w += MS * D;
  char* Ql8 = w; w += MS * D;
  char* Kh8 = w; w += MS * D;
  char* Kl8 = w; w += MS * D;
  ushort_t* Vt  = (ushort_t*)w; w += MS * D * 2;   // bf16 [B][D][S]
  char* WH8 = w; w += (long)2 * D * D;             // [2048][1024] Q rows then K
  char* WL8 = w; w += (long)2 * D * D;
  ushort_t* Wvh = (ushort_t*)w; w += (long)D * D * 2;
  // batch-PAIR score buffer: [8192][4096] i16 = 67.1MB aliasing
  // Xhi (33.55MB) + Xh8+Xl8 (33.55MB contiguous) — both dead by then.
  short* sc = (short*)d_ws;

  const int n4x = (int)(MS * D / 4);
  const int n4w = D * D / 4;
  cast_split<<<(n4x + 255) / 256, 256, 0, stream>>>(X, Xhi, Xh8, Xl8, n4x);
  cast_wqk<<<dim3((n4w + 255) / 256, 2), 256, 0, stream>>>(
      Wq, Wk, WH8, WL8, WH8 + (long)D * D, WL8 + (long)D * D, n4w);
  cast_wv<<<(n4w + 255) / 256, 256, 0, stream>>>(Wv, Wvh, n4w);

  dim3 blk(256);
  // Q proj (all rows) -> dual-i8
  proj_i8<0><<<dim3(MS / 128, D / 64), blk, 0, stream>>>(
      Xh8, Xl8, WH8, WL8, Qh8, Ql8, len);
  // K proj (row-skip) -> dual-i8 (W cols 1024..2047 of stacked buffer)
  proj_i8<3><<<dim3(MS / 128, D / 64), blk, 0, stream>>>(
      Xh8, Xl8, WH8 + (long)D * D, WL8 + (long)D * D, Kh8, Kl8, len);
  // V proj (row-skip) -> bf16 transposed [B][D][S]
  gemm_bt<4, 4, 2, 3><<<dim3(MS / 128, D / 128, 1), blk, 0, stream>>>(
      Xhi, Wvh, Vt, D, D, S, (long)D * S, len, 0, 0, 0, 0);

  for (int p = 0; p < 2; ++p) {
    const int b0 = 2 * p;
    const long so = (long)b0 * S * D;
    qk_i8<<<dim3(S / 128, S / 64, 2), blk, 0, stream>>>(
        Qh8 + so, Ql8 + so, Kh8 + so, Kl8 + so, sc, len, b0);
    softmax_rows<<<2 * S, 256, 0, stream>>>(sc, len, b0);
    gemm_bt<4, 2, 0, 2><<<dim3(S / 128, D / 64, 2), blk, 0, stream>>>(
        (const ushort_t*)sc, Vt + (long)b0 * D * S, out + so, S, S, D, 0,
        len, b0, (long)S * 4096, (long)D * S, (long)S * D);
  }
}

// Round 16
// 583.421 us; speedup vs baseline: 1.0368x; 1.0368x over previous
//
#include <hip/hip_runtime.h>

// ---------------------------------------------------------------------------
// Self-attention (B=4, S=4096, D=1024), fp32 in/out.
// R19: AI > occupancy for stream-stream GEMMs (R18 measured: qk 128x64/3blk
//  99.5us WORSE than 128x128/2blk 90.9us). Revert qk to 128x128; apply same
//  lesson to PV: TN=2 -> TN=4 (128x128, 16 FLOP/B vs 10.7, 16 MFMA/chunk).
//  Under pair-batching PV grid is 512 blocks at TN=4 (>=2/CU, 32KB LDS).
//  Accumulation chains unchanged -> bit-identical.
// R16 kept: strength-reduced XOR addressing, split Q/K proj (weights L2-
// reused so proj keeps 128x64), pair-batched attention, 2-buf/1-deep
// counted vmcnt. NOTE: MfmaUtil under-reports i8 (gfx94x formula).
// Numerics: proj 4-term dual-i8 (X=(xh+xl/256)/16, W=(wh+wl/256)/512),
// QK^T dual-i8 3-term, scores i16 (logit*32), V/PV bf16. absmax 0.08984375.
// ---------------------------------------------------------------------------

typedef __attribute__((ext_vector_type(4))) float floatx4;
typedef __attribute__((ext_vector_type(4))) int intx4;
typedef __attribute__((ext_vector_type(8))) short shortx8;
typedef unsigned short ushort_t;

__device__ __forceinline__ ushort_t f2bf(float f) {
  union { float f; unsigned u; } x; x.f = f;
  unsigned r = x.u + 0x7fffu + ((x.u >> 16) & 1u);  // RNE
  return (ushort_t)(r >> 16);
}
__device__ __forceinline__ float bf2f(ushort_t h) {
  union { unsigned u; float f; } x; x.u = ((unsigned)h) << 16; return x.f;
}
// fixed-point dual-int8 quant: v ~= (qh + ql/256) / 16   (activations, Q, K)
__device__ __forceinline__ void quant8(float v, char& qh, char& ql) {
  float vs = v * 16.0f;
  float h = rintf(vs);
  h = fminf(fmaxf(h, -127.f), 127.f);
  float l = rintf((vs - h) * 256.0f);
  l = fminf(fmaxf(l, -127.f), 127.f);
  qh = (char)(int)h; ql = (char)(int)l;
}
// weight quant: v ~= (qh + ql/256) / 512
__device__ __forceinline__ void quant8w(float v, char& qh, char& ql) {
  float vs = v * 512.0f;
  float h = rintf(vs);
  h = fminf(fmaxf(h, -127.f), 127.f);
  float l = rintf((vs - h) * 256.0f);
  l = fminf(fmaxf(l, -127.f), 127.f);
  qh = (char)(int)h; ql = (char)(int)l;
}

// Async global->LDS, 16B per lane (m97 lever). LDS dest = wave-uniform base
// + lane*16 (m104/m108); lane->LDS mapping contiguous in lane order.
__device__ __forceinline__ void gload_lds16(const void* g, void* l) {
  __builtin_amdgcn_global_load_lds(
      (__attribute__((address_space(1))) void*)(uintptr_t)g,
      (__attribute__((address_space(3))) void*)(unsigned)(uintptr_t)l,
      16, 0, 0);
}

// Counted vmcnt wait (T4). Never 0 in the main loop.
template<int N> __device__ __forceinline__ void wait_vm() {
  static_assert(N == 0 || N == 3 || N == 4 || N == 6 || N == 8, "bad vmcnt");
  if constexpr (N == 0)       asm volatile("s_waitcnt vmcnt(0)" ::: "memory");
  else if constexpr (N == 3)  asm volatile("s_waitcnt vmcnt(3)" ::: "memory");
  else if constexpr (N == 4)  asm volatile("s_waitcnt vmcnt(4)" ::: "memory");
  else if constexpr (N == 6)  asm volatile("s_waitcnt vmcnt(6)" ::: "memory");
  else if constexpr (N == 8)  asm volatile("s_waitcnt vmcnt(8)" ::: "memory");
}
__device__ __forceinline__ void barrier_fenced() {
  asm volatile("" ::: "memory");
  __builtin_amdgcn_s_barrier();
  asm volatile("" ::: "memory");
}

// ---------------- bf16 GEMM (V proj / PV): C = A * B^T ---------------------
// Tile BM=TM*32 x BN=TN*32, 256 threads = 4 waves 2x2. Double-buffered LDS,
// 1-deep prefetch, counted vmcnt, XOR buffer addressing.
// OMODE: 0 = C fp32 [z*sC+row*ldc+col]; 2 = C bf16 per-batch transposed.
// LMODE: 2 kend=roundup(sent(b0+z),128) (PV);
//        3 skip block if (row0&4095)>=roundup(sent(row0>>12),128) (V proj)
template<int TM, int TN, int OMODE, int LMODE>
__global__ __launch_bounds__(256)
void gemm_bt(const ushort_t* __restrict__ A0g, const ushort_t* __restrict__ B0g,
             void* __restrict__ C0v, int K, int lda, int ldc, long bstride,
             const int* __restrict__ lenp, int b0, long sA, long sB, long sC)
{
  constexpr int BM = TM * 32, BN = TN * 32;
  constexpr int LA = TM / 2, LB = TN / 2;
  constexpr int NL = LA + LB;
  constexpr unsigned ABUF = BM * 32 * 2;      // bytes per A buffer (pow2)
  constexpr unsigned BBUF = BN * 32 * 2;      // bytes per B buffer (pow2)
  __shared__ ushort_t As[2][BM][32];
  __shared__ ushort_t Bs[2][BN][32];

  const int tid = threadIdx.x;
  const int z = blockIdx.z;
  const long row0 = (long)blockIdx.x * BM;
  const long col0 = (long)blockIdx.y * BN;

  int kend = K;
  if constexpr (LMODE == 2) {
    const int sent = lenp[b0 + z] * 2;
    kend = (sent + 127) & ~127;
  } else if constexpr (LMODE == 3) {
    const int sent = lenp[row0 >> 12] * 2;
    if ((int)(row0 & 4095) >= ((sent + 127) & ~127)) return;
  }

  const int sr = tid >> 2, scol = (tid & 3) * 8;
  // per-stream global pointers, advanced += 32 elems (64B) per chunk
  const ushort_t* pA[LA];
  const ushort_t* pB[LB];
#pragma unroll
  for (int j = 0; j < LA; ++j)
    pA[j] = A0g + z * sA + (row0 + sr + j * 64) * (long)lda + scol;
#pragma unroll
  for (int j = 0; j < LB; ++j)
    pB[j] = B0g + z * sB + (col0 + sr + j * 64) * (long)K + scol;
  // LDS dest byte offsets (buf0), toggled by XOR
  unsigned dA = (unsigned)(sr * 32 + scol) * 2;
  unsigned dB = dA;

  const int wid = tid >> 6, lane = tid & 63;
  const int wm = (wid >> 1) * (BM / 2), wn = (wid & 1) * (BN / 2);
  const int lr = lane & 15, lq = lane >> 4;
  // LDS read byte offsets (buf0), toggled by XOR
  unsigned ra = (unsigned)((wm + lr) * 32 + lq * 8) * 2;
  unsigned rb = (unsigned)((wn + lr) * 32 + lq * 8) * 2;

  floatx4 acc[TM][TN] = {};

  auto stage = [&]() {
#pragma unroll
    for (int j = 0; j < LA; ++j)
      gload_lds16(pA[j], (char*)As + dA + j * 4096);
#pragma unroll
    for (int j = 0; j < LB; ++j)
      gload_lds16(pB[j], (char*)Bs + dB + j * 4096);
  };
  auto advance = [&]() {
#pragma unroll
    for (int j = 0; j < LA; ++j) pA[j] += 32;
#pragma unroll
    for (int j = 0; j < LB; ++j) pB[j] += 32;
  };

  const int nk = kend >> 5;
  stage(); advance();
  dA ^= ABUF; dB ^= BBUF;
  for (int t = 0; t < nk; ++t) {
    if (t + 1 < nk) { stage(); advance(); dA ^= ABUF; dB ^= BBUF; wait_vm<NL>(); }
    else            { wait_vm<0>(); }
    barrier_fenced();

    const char* Ab = (const char*)As + ra;
    const char* Bb = (const char*)Bs + rb;
    shortx8 af[TM], bf[TN];
#pragma unroll
    for (int tt = 0; tt < TM; ++tt)
      af[tt] = *(const shortx8*)(Ab + tt * 1024);
#pragma unroll
    for (int tt = 0; tt < TN; ++tt)
      bf[tt] = *(const shortx8*)(Bb + tt * 1024);
#pragma unroll
    for (int mt = 0; mt < TM; ++mt)
#pragma unroll
      for (int nt = 0; nt < TN; ++nt)
        acc[mt][nt] = __builtin_amdgcn_mfma_f32_16x16x32_bf16(af[mt], bf[nt], acc[mt][nt], 0, 0, 0);

    barrier_fenced();
    ra ^= ABUF; rb ^= BBUF;
  }

  // C/D layout (m89/m91): col = lane&15, row = (lane>>4)*4 + reg
#pragma unroll
  for (int mt = 0; mt < TM; ++mt) {
#pragma unroll
    for (int nt = 0; nt < TN; ++nt) {
      long col = col0 + wn + nt * 16 + lr;
      if constexpr (OMODE == 2) {
        long row = row0 + wm + mt * 16 + lq * 4;
        long bb = row >> 12, s = row & 4095;
        ushort4 pk;
        pk.x = f2bf(acc[mt][nt][0]); pk.y = f2bf(acc[mt][nt][1]);
        pk.z = f2bf(acc[mt][nt][2]); pk.w = f2bf(acc[mt][nt][3]);
        *(ushort4*)&((ushort_t*)C0v)[bb * bstride + col * ldc + s] = pk;
      } else {
#pragma unroll
        for (int r = 0; r < 4; ++r) {
          long row = row0 + wm + mt * 16 + lq * 4 + r;
          ((float*)C0v)[z * sC + row * ldc + col] = acc[mt][nt][r];
        }
      }
    }
  }
}

// ---------------- dual-i8 projection: C = X * W^T --------------------------
// X = (xh+xl/256)/16, W = (wh+wl/256)/512; 4 exact i32 accum terms:
//   v = (hh + cross/256 + ll/65536) / 8192 -> re-quant dual-i8 scale 16.
// Tile 128x64, K=1024 in 64-chunks. Dbuf 1-deep, XOR addressing.
// LMODE 0 = all rows (Q); LMODE 3 = row-block skip (K).
template<int LMODE>
__global__ __launch_bounds__(256)
void proj_i8(const char* __restrict__ Ah, const char* __restrict__ Al,
             const char* __restrict__ Bh, const char* __restrict__ Bl,
             char* __restrict__ Ch, char* __restrict__ Cl,
             const int* __restrict__ lenp)
{
  __shared__ char As[2][2][128][64];   // [buf][h/l]   buf stride 16384
  __shared__ char Bs[2][2][64][64];    // buf stride 8192
  const int tid = threadIdx.x;
  const long row0 = (long)blockIdx.x * 128;
  const long col0 = (long)blockIdx.y * 64;
  if constexpr (LMODE == 3) {
    const int sent = lenp[row0 >> 12] * 2;
    if ((int)(row0 & 4095) >= ((sent + 127) & ~127)) return;
  }

  const int sr = tid >> 2, sc16 = (tid & 3) * 16;
  const char* gA0a = Ah + (row0 + sr) * 1024 + sc16;
  const char* gA0b = gA0a + 65536;
  const char* gA1a = Al + (row0 + sr) * 1024 + sc16;
  const char* gA1b = gA1a + 65536;
  const char* gB0 = Bh + (col0 + sr) * 1024 + sc16;
  const char* gB1 = Bl + (col0 + sr) * 1024 + sc16;
  unsigned dA = (unsigned)(sr * 64 + sc16);   // + hl*8192 + j*4096
  unsigned dB = dA;                            // + hl*4096

  const int wid = tid >> 6, lane = tid & 63;
  const int wm = (wid >> 1) * 64, wn = (wid & 1) * 32;
  const int lr = lane & 15, lq = lane >> 4;
  unsigned ra = (unsigned)((wm + lr) * 64 + lq * 16);
  unsigned rb = (unsigned)((wn + lr) * 64 + lq * 16);

  intx4 acc1[4][2] = {};   // xh*wh
  intx4 acc2[4][2] = {};   // xh*wl + xl*wh   (/256)
  intx4 acc3[4][2] = {};   // xl*wl           (/65536)

  auto stage = [&]() {
    gload_lds16(gA0a, (char*)As + dA);
    gload_lds16(gA0b, (char*)As + dA + 4096);
    gload_lds16(gA1a, (char*)As + dA + 8192);
    gload_lds16(gA1b, (char*)As + dA + 8192 + 4096);
    gload_lds16(gB0, (char*)Bs + dB);
    gload_lds16(gB1, (char*)Bs + dB + 4096);
  };
  auto advance = [&]() {
    gA0a += 64; gA0b += 64; gA1a += 64; gA1b += 64; gB0 += 64; gB1 += 64;
  };

  stage(); advance();
  dA ^= 16384; dB ^= 8192;
  for (int t = 0; t < 16; ++t) {
    if (t + 1 < 16) { stage(); advance(); dA ^= 16384; dB ^= 8192; wait_vm<6>(); }
    else            { wait_vm<0>(); }
    barrier_fenced();

    const char* Ab = (const char*)As + ra;
    const char* Bb = (const char*)Bs + rb;
    intx4 ah[4], al[4], bh[2], bl[2];
#pragma unroll
    for (int tt = 0; tt < 4; ++tt) {
      ah[tt] = *(const intx4*)(Ab + tt * 1024);
      al[tt] = *(const intx4*)(Ab + 8192 + tt * 1024);
    }
#pragma unroll
    for (int tt = 0; tt < 2; ++tt) {
      bh[tt] = *(const intx4*)(Bb + tt * 1024);
      bl[tt] = *(const intx4*)(Bb + 4096 + tt * 1024);
    }
#pragma unroll
    for (int mt = 0; mt < 4; ++mt)
#pragma unroll
      for (int nt = 0; nt < 2; ++nt) {
        acc1[mt][nt] = __builtin_amdgcn_mfma_i32_16x16x64_i8(ah[mt], bh[nt], acc1[mt][nt], 0, 0, 0);
        acc2[mt][nt] = __builtin_amdgcn_mfma_i32_16x16x64_i8(ah[mt], bl[nt], acc2[mt][nt], 0, 0, 0);
        acc2[mt][nt] = __builtin_amdgcn_mfma_i32_16x16x64_i8(al[mt], bh[nt], acc2[mt][nt], 0, 0, 0);
        acc3[mt][nt] = __builtin_amdgcn_mfma_i32_16x16x64_i8(al[mt], bl[nt], acc3[mt][nt], 0, 0, 0);
      }
    barrier_fenced();
    ra ^= 16384; rb ^= 8192;
  }

#pragma unroll
  for (int mt = 0; mt < 4; ++mt)
#pragma unroll
    for (int nt = 0; nt < 2; ++nt) {
      long col = col0 + wn + nt * 16 + lr;
#pragma unroll
      for (int r = 0; r < 4; ++r) {
        long row = row0 + wm + mt * 16 + lq * 4 + r;
        float v = ((float)acc1[mt][nt][r]
                   + (float)acc2[mt][nt][r] * (1.0f / 256.0f)
                   + (float)acc3[mt][nt][r] * (1.0f / 65536.0f)) * (1.0f / 8192.0f);
        char qh, ql;
        quant8(v, qh, ql);
        Ch[row * 1024 + col] = qh;
        Cl[row * 1024 + col] = ql;
      }
    }
}

// ---------------- int8 QK^T -> i16 scores (logit*32) -----------------------
// Tile 128x128 (R16 measured-best), K=1024 in 64-chunks. 16x16x64 i8,
// 2 accums (hh, cross). Dbuf 1-deep, XOR addressing. blockIdx.z = batch.
__global__ __launch_bounds__(256)
void qk_i8(const char* __restrict__ Qh, const char* __restrict__ Ql,
           const char* __restrict__ Kh, const char* __restrict__ Kl,
           short* __restrict__ sc, const int* __restrict__ lenp, int b0)
{
  __shared__ char As[2][2][128][64];   // buf stride 16384
  __shared__ char Bs[2][2][128][64];   // buf stride 16384
  const int tid = threadIdx.x;
  const int z = blockIdx.z;
  const long zo = (long)z * 4096 * 1024;
  const long row0 = (long)blockIdx.x * 128;
  const long col0 = (long)blockIdx.y * 128;
  const int sent = lenp[b0 + z] * 2;
  if (col0 >= sent) return;

  const int sr = tid >> 2, sc16 = (tid & 3) * 16;
  const char* gA0a = Qh + zo + (row0 + sr) * 1024 + sc16;
  const char* gA0b = gA0a + 65536;
  const char* gA1a = Ql + zo + (row0 + sr) * 1024 + sc16;
  const char* gA1b = gA1a + 65536;
  const char* gB0a = Kh + zo + (col0 + sr) * 1024 + sc16;
  const char* gB0b = gB0a + 65536;
  const char* gB1a = Kl + zo + (col0 + sr) * 1024 + sc16;
  const char* gB1b = gB1a + 65536;
  unsigned dA = (unsigned)(sr * 64 + sc16);
  unsigned dB = dA;

  const int wid = tid >> 6, lane = tid & 63;
  const int wm = (wid >> 1) * 64, wn = (wid & 1) * 64;
  const int lr = lane & 15, lq = lane >> 4;
  unsigned ra = (unsigned)((wm + lr) * 64 + lq * 16);
  unsigned rb = (unsigned)((wn + lr) * 64 + lq * 16);

  intx4 acc1[4][4] = {};   // qh*kh
  intx4 acc2[4][4] = {};   // qh*kl + ql*kh (shared scale /256)

  auto stage = [&]() {
    gload_lds16(gA0a, (char*)As + dA);
    gload_lds16(gA0b, (char*)As + dA + 4096);
    gload_lds16(gA1a, (char*)As + dA + 8192);
    gload_lds16(gA1b, (char*)As + dA + 8192 + 4096);
    gload_lds16(gB0a, (char*)Bs + dB);
    gload_lds16(gB0b, (char*)Bs + dB + 4096);
    gload_lds16(gB1a, (char*)Bs + dB + 8192);
    gload_lds16(gB1b, (char*)Bs + dB + 8192 + 4096);
  };
  auto advance = [&]() {
    gA0a += 64; gA0b += 64; gA1a += 64; gA1b += 64;
    gB0a += 64; gB0b += 64; gB1a += 64; gB1b += 64;
  };

  stage(); advance();
  dA ^= 16384; dB ^= 16384;
  for (int t = 0; t < 16; ++t) {
    if (t + 1 < 16) { stage(); advance(); dA ^= 16384; dB ^= 16384; wait_vm<8>(); }
    else            { wait_vm<0>(); }
    barrier_fenced();

    const char* Ab = (const char*)As + ra;
    const char* Bb = (const char*)Bs + rb;
    intx4 ah[4], al[4], bh[4], bl[4];
#pragma unroll
    for (int tt = 0; tt < 4; ++tt) {
      ah[tt] = *(const intx4*)(Ab + tt * 1024);
      al[tt] = *(const intx4*)(Ab + 8192 + tt * 1024);
      bh[tt] = *(const intx4*)(Bb + tt * 1024);
      bl[tt] = *(const intx4*)(Bb + 8192 + tt * 1024);
    }
#pragma unroll
    for (int mt = 0; mt < 4; ++mt)
#pragma unroll
      for (int nt = 0; nt < 4; ++nt) {
        acc1[mt][nt] = __builtin_amdgcn_mfma_i32_16x16x64_i8(ah[mt], bh[nt], acc1[mt][nt], 0, 0, 0);
        acc2[mt][nt] = __builtin_amdgcn_mfma_i32_16x16x64_i8(ah[mt], bl[nt], acc2[mt][nt], 0, 0, 0);
        acc2[mt][nt] = __builtin_amdgcn_mfma_i32_16x16x64_i8(al[mt], bh[nt], acc2[mt][nt], 0, 0, 0);
      }
    barrier_fenced();
    ra ^= 16384; rb ^= 16384;
  }

  // i16 = logit*32 = acc1/8 + acc2/2048
  short* scz = sc + (long)z * 4096 * 4096;
#pragma unroll
  for (int mt = 0; mt < 4; ++mt)
#pragma unroll
    for (int nt = 0; nt < 4; ++nt) {
      long col = col0 + wn + nt * 16 + lr;
#pragma unroll
      for (int r = 0; r < 4; ++r) {
        long row = row0 + wm + mt * 16 + lq * 4 + r;
        float v = (float)acc1[mt][nt][r] * 0.125f
                + (float)acc2[mt][nt][r] * (1.0f / 2048.0f);
        v = fminf(fmaxf(v, -32000.0f), 32000.0f);
        scz[row * 4096 + col] = (short)(int)rintf(v);
      }
    }
}

// ---------------- casts ----------------------------------------------------
__global__ __launch_bounds__(256)
void cast_split(const float* __restrict__ in, ushort_t* __restrict__ hi,
                char* __restrict__ qh, char* __restrict__ ql, int n4) {
  int i = blockIdx.x * 256 + threadIdx.x;
  if (i < n4) {
    float4 v = ((const float4*)in)[i];
    ushort4 h;
    h.x = f2bf(v.x); h.y = f2bf(v.y); h.z = f2bf(v.z); h.w = f2bf(v.w);
    ((ushort4*)hi)[i] = h;
    char ax, bx, ay, by, az, bz, aw, bw;
    quant8(v.x, ax, bx); quant8(v.y, ay, by);
    quant8(v.z, az, bz); quant8(v.w, aw, bw);
    char4 a, b;
    a.x = ax; a.y = ay; a.z = az; a.w = aw;
    b.x = bx; b.y = by; b.z = bz; b.w = bw;
    ((char4*)qh)[i] = a;
    ((char4*)ql)[i] = b;
  }
}

__global__ __launch_bounds__(256)
void cast_wqk(const float* __restrict__ w0, const float* __restrict__ w1,
              char* __restrict__ h0, char* __restrict__ l0,
              char* __restrict__ h1, char* __restrict__ l1, int n4) {
  int i = blockIdx.x * 256 + threadIdx.x;
  if (i >= n4) return;
  const float* in = blockIdx.y ? w1 : w0;
  char* hp = blockIdx.y ? h1 : h0;
  char* lp = blockIdx.y ? l1 : l0;
  float4 v = ((const float4*)in)[i];
  char ax, bx, ay, by, az, bz, aw, bw;
  quant8w(v.x, ax, bx); quant8w(v.y, ay, by);
  quant8w(v.z, az, bz); quant8w(v.w, aw, bw);
  char4 a, b;
  a.x = ax; a.y = ay; a.z = az; a.w = aw;
  b.x = bx; b.y = by; b.z = bz; b.w = bw;
  ((char4*)hp)[i] = a;
  ((char4*)lp)[i] = b;
}

__global__ __launch_bounds__(256)
void cast_wv(const float* __restrict__ w, ushort_t* __restrict__ h, int n4) {
  int i = blockIdx.x * 256 + threadIdx.x;
  if (i >= n4) return;
  float4 v = ((const float4*)w)[i];
  ushort4 p;
  p.x = f2bf(v.x); p.y = f2bf(v.y); p.z = f2bf(v.z); p.w = f2bf(v.w);
  ((ushort4*)h)[i] = p;
}

// Masked softmax; reads i16 scores (logit*32), writes bf16 P in place.
// Handles a batch PAIR: rows 0..8191, b = b0 + (row>>12).
__global__ __launch_bounds__(256)
void softmax_rows(short* __restrict__ scores, const int* __restrict__ length, int b0) {
  const long row = blockIdx.x;
  const int b = b0 + (int)(row >> 12);
  short* p = scores + row * 4096;
  const int sent = length[b] * 2;
  const int sentceil = (sent + 127) & ~127;
  const int tid = threadIdx.x;
  float vals[16];
  float mx = -3.4e38f;
  int nj = 0;
  for (int c = tid; c < sentceil; c += 256) {
    float v = (float)p[c] * (1.0f / 32.0f);
    v = (c < sent) ? v : -2147483648.0f;   // NEG_BIG
    vals[nj++] = v;
    mx = fmaxf(mx, v);
  }
#pragma unroll
  for (int off = 32; off > 0; off >>= 1) mx = fmaxf(mx, __shfl_down(mx, off));
  __shared__ float red[8];
  if ((tid & 63) == 0) red[tid >> 6] = mx;
  __syncthreads();
  mx = fmaxf(fmaxf(red[0], red[1]), fmaxf(red[2], red[3]));
  float sum = 0.f;
  for (int j = 0; j < nj; ++j) { vals[j] = __expf(vals[j] - mx); sum += vals[j]; }
#pragma unroll
  for (int off = 32; off > 0; off >>= 1) sum += __shfl_down(sum, off);
  __syncthreads();
  if ((tid & 63) == 0) red[tid >> 6] = sum;
  __syncthreads();
  float inv = 1.0f / (red[0] + red[1] + red[2] + red[3]);
  ushort_t* pb = (ushort_t*)p;
  int j = 0;
  for (int c = tid; c < sentceil; c += 256) pb[c] = f2bf(vals[j++] * inv);
}

extern "C" void kernel_launch(void* const* d_in, const int* in_sizes, int n_in,
                              void* d_out, int out_size, void* d_ws, size_t ws_size,
                              hipStream_t stream) {
  const float* X   = (const float*)d_in[0];
  const int*   len = (const int*)d_in[1];
  const float* Wq  = (const float*)d_in[2];
  const float* Wk  = (const float*)d_in[3];
  const float* Wv  = (const float*)d_in[4];
  float* out = (float*)d_out;

  const int Bn = 4, S = 4096, D = 1024;
  const long MS = (long)Bn * S;

  char* w = (char*)d_ws;
  ushort_t* Xhi = (ushort_t*)w; w += MS * D * 2;   // dead after V proj
  char* Xh8 = w; w += MS * D;                      // dead after proj
  char* Xl8 = w; w += MS * D;                      // dead after proj
  char* Qh8 = w; w += MS * D;
  char* Ql8 = w; w += MS * D;
  char* Kh8 = w; w += MS * D;
  char* Kl8 = w; w += MS * D;
  ushort_t* Vt  = (ushort_t*)w; w += MS * D * 2;   // bf16 [B][D][S]
  char* WH8 = w; w += (long)2 * D * D;             // [2048][1024] Q rows then K
  char* WL8 = w; w += (long)2 * D * D;
  ushort_t* Wvh = (ushort_t*)w; w += (long)D * D * 2;
  // batch-PAIR score buffer: [8192][4096] i16 = 67.1MB aliasing
  // Xhi (33.55MB) + Xh8+Xl8 (33.55MB contiguous) — both dead by then.
  short* sc = (short*)d_ws;

  const int n4x = (int)(MS * D / 4);
  const int n4w = D * D / 4;
  cast_split<<<(n4x + 255) / 256, 256, 0, stream>>>(X, Xhi, Xh8, Xl8, n4x);
  cast_wqk<<<dim3((n4w + 255) / 256, 2), 256, 0, stream>>>(
      Wq, Wk, WH8, WL8, WH8 + (long)D * D, WL8 + (long)D * D, n4w);
  cast_wv<<<(n4w + 255) / 256, 256, 0, stream>>>(Wv, Wvh, n4w);

  dim3 blk(256);
  // Q proj (all rows) -> dual-i8
  proj_i8<0><<<dim3(MS / 128, D / 64), blk, 0, stream>>>(
      Xh8, Xl8, WH8, WL8, Qh8, Ql8, len);
  // K proj (row-skip) -> dual-i8 (W cols 1024..2047 of stacked buffer)
  proj_i8<3><<<dim3(MS / 128, D / 64), blk, 0, stream>>>(
      Xh8, Xl8, WH8 + (long)D * D, WL8 + (long)D * D, Kh8, Kl8, len);
  // V proj (row-skip) -> bf16 transposed [B][D][S]
  gemm_bt<4, 4, 2, 3><<<dim3(MS / 128, D / 128, 1), blk, 0, stream>>>(
      Xhi, Wvh, Vt, D, D, S, (long)D * S, len, 0, 0, 0, 0);

  for (int p = 0; p < 2; ++p) {
    const int b0 = 2 * p;
    const long so = (long)b0 * S * D;
    qk_i8<<<dim3(S / 128, S / 128, 2), blk, 0, stream>>>(
        Qh8 + so, Ql8 + so, Kh8 + so, Kl8 + so, sc, len, b0);
    softmax_rows<<<2 * S, 256, 0, stream>>>(sc, len, b0);
    gemm_bt<4, 4, 0, 2><<<dim3(S / 128, D / 128, 2), blk, 0, stream>>>(
        (const ushort_t*)sc, Vt + (long)b0 * D * S, out + so, S, S, D, 0,
        len, b0, (long)S * 4096, (long)D * S, (long)S * D);
  }
}